// Round 14
// baseline (299.714 us; speedup 1.0000x reference)
//
#include <hip/hip_runtime.h>
#include <hip/hip_fp16.h>
#include <type_traits>

#define N_NODES 100000
#define N_EDGES 1280000
#define N_GRAPHS 512
#define NBK 196          // buckets of 512 dst nodes: ceil(100000/512)
#define CHUNK 3200       // edges per scatter block; 400*3200 == N_EDGES exactly
#define NCH 400
#define CAP 8192         // per-bucket region capacity: mean 6554, sigma ~81 -> 20 sigma
#define CAPH 4096        // per-HALF-bucket LDS capacity: mean 3277, sigma ~57 -> 14 sigma
#define GEMM_BLOCKS 391  // ceil(100000/256)

typedef _Float16 v8h __attribute__((ext_vector_type(8)));
typedef float v4f __attribute__((ext_vector_type(4)));

// fp16 x fp32 + fp32 fused (one VALU op; fp16 operand widened exactly in the FMA)
__device__ inline void fmix_lo(float& acc, unsigned h2, float n) {
    asm volatile("v_fma_mix_f32 %0, %1, %2, %0 op_sel:[0,0,0] op_sel_hi:[1,0,0]"
                 : "+v"(acc) : "v"(h2), "v"(n));
}
__device__ inline void fmix_hi(float& acc, unsigned h2, float n) {
    asm volatile("v_fma_mix_f32 %0, %1, %2, %0 op_sel:[1,0,0] op_sel_hi:[1,0,0]"
                 : "+v"(acc) : "v"(h2), "v"(n));
}

// ---------------- W prep: W1,W2 -> fp16 transposed [n][k]; also zero bcur ------

__global__ __launch_bounds__(256) void wprep(const float* __restrict__ w1,
                                             const float* __restrict__ w2,
                                             _Float16* __restrict__ wt1,
                                             _Float16* __restrict__ wt2,
                                             int* __restrict__ bcur) {
    int t = threadIdx.x;
    const float* W = blockIdx.x ? w2 : w1;
    _Float16*    O = blockIdx.x ? wt2 : wt1;
    #pragma unroll
    for (int q = 0; q < 16; q++) {
        int idx = t + q * 256;            // W is [k][n] row-major
        int k = idx >> 6, n = idx & 63;
        O[n * 64 + k] = (_Float16)W[idx]; // O[n][k]
    }
    for (int i = t + blockIdx.x * 2048; i < (blockIdx.x + 1) * 2048; i += 256)
        bcur[i] = 0;                      // 4096 ints total
}

// ---------------- MFMA GEMM body [256 rows x 64] @ [64 x 64] -------------------
// Wave = 16 nodes x 64 cols; A-frag A[m=lane&15][k=quad*8+j]; C/D col=lane&15,
// row=quad*4+reg (m89/m120-verified). fp32 accumulate. Used by scatter_gemm
// for layer-1 X@W0 (unfolded).

__device__ inline void gemm_body_f32(int bid, const float* __restrict__ X,
                                     const float* __restrict__ W,
                                     __half* __restrict__ H,
                                     _Float16 (*Wt)[72]) {
    int t = threadIdx.x;
    #pragma unroll
    for (int q = 0; q < 4; q++) {         // stage + transpose W as half
        int idx = t + q * 256;
        int k = idx >> 4;
        int n0 = (idx & 15) * 4;
        float4 v = ((const float4*)W)[idx];
        Wt[n0 + 0][k] = (_Float16)v.x;
        Wt[n0 + 1][k] = (_Float16)v.y;
        Wt[n0 + 2][k] = (_Float16)v.z;
        Wt[n0 + 3][k] = (_Float16)v.w;
    }
    __syncthreads();

    int wv = t >> 6, lane = t & 63;
    int m = lane & 15, quad = lane >> 4;

    v8h bf[4][2];
    #pragma unroll
    for (int c = 0; c < 4; c++)
        #pragma unroll
        for (int h = 0; h < 2; h++)
            bf[c][h] = *(const v8h*)&Wt[c * 16 + m][h * 32 + quad * 8];

    int base = bid * 256 + wv * 64;
    #pragma unroll
    for (int tt = 0; tt < 4; tt++) {
        int tile = base + tt * 16;
        int rA = min(tile + m, N_NODES - 1);
        const float* xp = X + (size_t)rA * 64 + quad * 8;
        float4 p0 = *(const float4*)xp;
        float4 p1 = *(const float4*)(xp + 4);
        float4 p2 = *(const float4*)(xp + 32);
        float4 p3 = *(const float4*)(xp + 36);
        v8h a0 = (v8h){(_Float16)p0.x, (_Float16)p0.y, (_Float16)p0.z, (_Float16)p0.w,
                       (_Float16)p1.x, (_Float16)p1.y, (_Float16)p1.z, (_Float16)p1.w};
        v8h a1 = (v8h){(_Float16)p2.x, (_Float16)p2.y, (_Float16)p2.z, (_Float16)p2.w,
                       (_Float16)p3.x, (_Float16)p3.y, (_Float16)p3.z, (_Float16)p3.w};
        v4f acc[4];
        #pragma unroll
        for (int c = 0; c < 4; c++) {
            acc[c] = (v4f){0.f, 0.f, 0.f, 0.f};
            acc[c] = __builtin_amdgcn_mfma_f32_16x16x32_f16(a0, bf[c][0], acc[c], 0, 0, 0);
            acc[c] = __builtin_amdgcn_mfma_f32_16x16x32_f16(a1, bf[c][1], acc[c], 0, 0, 0);
        }
        #pragma unroll
        for (int r = 0; r < 4; r++) {
            int row = tile + quad * 4 + r;
            if (row < N_NODES) {
                __half* hp = H + (size_t)row * 64 + m;
                #pragma unroll
                for (int c = 0; c < 4; c++)
                    hp[c * 16] = __float2half(acc[c][r]);
            }
        }
    }
}

// ---------------- fused: edge scatter (blocks 0..NCH-1) + gemm1 (rest) ---------
// Scatter: LDS-staged, one contiguous run per bucket per block (single atomic
// on padded cursor) -> full-line writes from one CU (R5 lesson). gemm1 runs
// unfolded (dinv not computed yet); layer-1 agg uses the FULL-norm variant.

#define SC_BUF   0                              // int2[CHUNK]           25600 B
#define SC_LCNT  (CHUNK * 8)                    // int[NBK]
#define SC_LLOC  (SC_LCNT + NBK * 4)            // int[NBK]
#define SC_LCUR  (SC_LLOC + NBK * 4)            // int[NBK]
#define SC_S     (SC_LCUR + NBK * 4)            // int[256]
#define SC_BYTES (SC_S + 256 * 4)               // ~29 KB

__global__ __launch_bounds__(256) void scatter_gemm(const int* __restrict__ src,
                                                    const int* __restrict__ dst,
                                                    int* __restrict__ bcur,
                                                    int2* __restrict__ pairs,
                                                    const float* __restrict__ x,
                                                    const float* __restrict__ w0,
                                                    __half* __restrict__ H) {
    alignas(16) __shared__ char smem[SC_BYTES];
    if (blockIdx.x >= NCH) {
        gemm_body_f32(blockIdx.x - NCH, x, w0, H, (_Float16(*)[72])smem);
        return;
    }
    int2* buf  = (int2*)(smem + SC_BUF);
    int*  lcnt = (int*)(smem + SC_LCNT);
    int*  lloc = (int*)(smem + SC_LLOC);
    int*  lcur = (int*)(smem + SC_LCUR);
    int*  s    = (int*)(smem + SC_S);
    int t = threadIdx.x;
    for (int k = t; k < NBK; k += 256) { lcnt[k] = 0; lcur[k] = 0; }
    __syncthreads();
    int e0 = blockIdx.x * CHUNK;
    for (int i = t; i < CHUNK; i += 256) atomicAdd(&lcnt[dst[e0 + i] >> 9], 1);
    __syncthreads();
    {   // exclusive scan of lcnt (NBK <= 256)
        int v = (t < NBK) ? lcnt[t] : 0;
        s[t] = v; __syncthreads();
        for (int d = 1; d < 256; d <<= 1) {
            int xx = (t >= d) ? s[t - d] : 0;
            __syncthreads();
            s[t] += xx;
            __syncthreads();
        }
        if (t < NBK) lloc[t] = s[t] - v;
    }
    __syncthreads();
    for (int i = t; i < CHUNK; i += 256) {
        int d = dst[e0 + i];
        int k = d >> 9;
        int li = lloc[k] + atomicAdd(&lcur[k], 1);
        buf[li] = make_int2(src[e0 + i], d);
    }
    __syncthreads();
    for (int k = t; k < NBK; k += 256) {
        int c = lcnt[k];
        if (c) {
            int g = atomicAdd(&bcur[k * 16], c);
            int lo = lloc[k];
            int2* dstp = pairs + (size_t)k * CAP;
            for (int j = 0; j < c; j++)
                if (g + j < CAP) dstp[g + j] = buf[lo + j];
        }
    }
}

// ---------------- per-half-bucket exact CSR + degree/dinv/offs ----------------

__global__ __launch_bounds__(256) void bucket_place(const int2* __restrict__ pairs,
                                                    const int* __restrict__ bcur,
                                                    int* __restrict__ offs,
                                                    float* __restrict__ dinv,
                                                    int* __restrict__ csr) {
    __shared__ int lcnt[256], lofs[256], lcur[256], red[256];
    __shared__ int lsrc[CAPH];                  // 16 KB
    int t = threadIdx.x;
    int bb = blockIdx.x;
    int b = bb >> 1, half = bb & 1;
    int node0 = (b << 9) + (half << 8);
    int nn = min(256, N_NODES - node0);
    red[t] = (t < b) ? min(bcur[t * 16], CAP) : 0;
    __syncthreads();
    for (int d = 128; d > 0; d >>= 1) {
        if (t < d) red[t] += red[t + d];
        __syncthreads();
    }
    int bbase = red[0];
    int cnt = min(bcur[b * 16], CAP);
    __syncthreads();
    lcnt[t] = 0; lcur[t] = 0;
    __syncthreads();
    const int2* prs = pairs + (size_t)b * CAP;
    for (int i = t; i < cnt; i += 256) {
        int n = prs[i].y - (b << 9);
        if ((n >> 8) == half) atomicAdd(&lcnt[n & 255], 1);
    }
    __syncthreads();
    int deg = lcnt[t];
    red[t] = deg; __syncthreads();
    for (int d = 1; d < 256; d <<= 1) {
        int xx = (t >= d) ? red[t - d] : 0;
        __syncthreads();
        red[t] += xx;
        __syncthreads();
    }
    lofs[t] = red[t] - deg;
    int total = red[255];
    int beg = bbase + (half ? (cnt - total) : 0);
    if (t < nn) {
        offs[node0 + t] = beg + lofs[t];
        dinv[node0 + t] = 1.0f / sqrtf((float)deg + 1.0f);
    }
    __syncthreads();
    for (int i = t; i < cnt; i += 256) {
        int2 pr = prs[i];
        int n = pr.y - (b << 9);
        if ((n >> 8) == half) {
            int li = lofs[n & 255] + atomicAdd(&lcur[n & 255], 1);
            if (li < CAPH) lsrc[li] = pr.x;
        }
    }
    __syncthreads();
    for (int j = t; j < total; j += 256) csr[beg + j] = lsrc[j];
    if (bb == 0 && t == 0) offs[N_NODES] = N_EDGES;
}

// ------------- aggregation body: wave per node, 4 edge-subgroups x 16 f-quads --
// Flat predicated 4-deep gather. FULL: per-edge weight dinv[src]*dinv[dst].
// !FULL: H pre-scaled by dinv -> broadcast di only. After the xor butterfly,
// ALL 64 lanes hold the full per-feature sums.

template <bool FULL>
__device__ inline void agg_body(const uint2* __restrict__ Hh, int wid, int lane,
                                const int* __restrict__ offs,
                                const int* __restrict__ csr,
                                const float* __restrict__ dinv,
                                float4& out) {
    int eg = lane >> 4;
    int fq = lane & 15;
    int beg = offs[wid], end = offs[wid + 1];
    float di = dinv[wid];
    uint2 us = Hh[wid * 16 + fq];

    float4 a0 = {0.f, 0.f, 0.f, 0.f};
    float4 a1 = {0.f, 0.f, 0.f, 0.f};
    for (int base = beg; base < end; base += 16) {
        int i0 = base + eg;
        int r0 = csr[i0], r1 = csr[i0 + 4], r2 = csr[i0 + 8], r3 = csr[i0 + 12];
        bool p0 = i0      < end, p1 = i0 + 4  < end,
             p2 = i0 + 8  < end, p3 = i0 + 12 < end;
        int s0 = p0 ? r0 : 0, s1 = p1 ? r1 : 0,
            s2 = p2 ? r2 : 0, s3 = p3 ? r3 : 0;
        uint2 u0 = Hh[(s0 << 4) + fq];
        uint2 u1 = Hh[(s1 << 4) + fq];
        uint2 u2 = Hh[(s2 << 4) + fq];
        uint2 u3 = Hh[(s3 << 4) + fq];
        float n0, n1, n2, n3;
        if constexpr (FULL) {
            float d0 = dinv[s0], d1 = dinv[s1], d2 = dinv[s2], d3 = dinv[s3];
            n0 = p0 ? d0 * di : 0.f;
            n1 = p1 ? d1 * di : 0.f;
            n2 = p2 ? d2 * di : 0.f;
            n3 = p3 ? d3 * di : 0.f;
        } else {
            n0 = p0 ? di : 0.f;
            n1 = p1 ? di : 0.f;
            n2 = p2 ? di : 0.f;
            n3 = p3 ? di : 0.f;
        }
        fmix_lo(a0.x, u0.x, n0); fmix_hi(a0.y, u0.x, n0);
        fmix_lo(a0.z, u0.y, n0); fmix_hi(a0.w, u0.y, n0);
        fmix_lo(a1.x, u1.x, n1); fmix_hi(a1.y, u1.x, n1);
        fmix_lo(a1.z, u1.y, n1); fmix_hi(a1.w, u1.y, n1);
        fmix_lo(a0.x, u2.x, n2); fmix_hi(a0.y, u2.x, n2);
        fmix_lo(a0.z, u2.y, n2); fmix_hi(a0.w, u2.y, n2);
        fmix_lo(a1.x, u3.x, n3); fmix_hi(a1.y, u3.x, n3);
        fmix_lo(a1.z, u3.y, n3); fmix_hi(a1.w, u3.y, n3);
    }
    a0.x += a1.x; a0.y += a1.y; a0.z += a1.z; a0.w += a1.w;
    a0.x += __shfl_xor(a0.x, 16); a0.y += __shfl_xor(a0.y, 16);
    a0.z += __shfl_xor(a0.z, 16); a0.w += __shfl_xor(a0.w, 16);
    a0.x += __shfl_xor(a0.x, 32); a0.y += __shfl_xor(a0.y, 32);
    a0.z += __shfl_xor(a0.z, 32); a0.w += __shfl_xor(a0.w, 32);
    float2 s01 = __half22float2(*(__half2*)&us.x);
    float2 s23 = __half22float2(*(__half2*)&us.y);
    float sw = FULL ? di * di : di;
    out.x = a0.x + s01.x * sw; out.y = a0.y + s01.y * sw;
    out.z = a0.z + s23.x * sw; out.w = a0.w + s23.y * sw;
}

// ---------- fused agg + next-layer GEMM: block = 4 nodes, 4 waves -------------
// Each wave aggregates 1 node; o = relu(r + bias) lands in a 4x64 LDS tile.
// After syncthreads each wave computes one 16-col tile of o @ W_next via MFMA
// (A rows 4..15 duplicate rows 0..3; junk outputs unwritten), folds dinv, and
// stores fp16. WT is pre-transposed fp16 [n][k] in global (L2-hot). 25000x4
// == N_NODES exactly -> no tail, all waves valid.

template <bool FULL>
__global__ __launch_bounds__(256) void agg_gemm(const __half* __restrict__ H,
                                                const int* __restrict__ offs,
                                                const int* __restrict__ csr,
                                                const float* __restrict__ dinv,
                                                const float* __restrict__ bias,
                                                const _Float16* __restrict__ WT,
                                                __half* __restrict__ O) {
    __shared__ _Float16 Xt[4][72];
    int wv = threadIdx.x >> 6, lane = threadIdx.x & 63;
    int wid = blockIdx.x * 4 + wv;
    float4 r;
    agg_body<FULL>((const uint2*)H, wid, lane, offs, csr, dinv, r);
    int fq = lane & 15, quad = lane >> 4;
    if (quad == 0) {
        float4 b4 = ((const float4*)bias)[fq];
        __half2 h01 = __float22half2_rn(make_float2(fmaxf(r.x + b4.x, 0.f),
                                                    fmaxf(r.y + b4.y, 0.f)));
        __half2 h23 = __float22half2_rn(make_float2(fmaxf(r.z + b4.z, 0.f),
                                                    fmaxf(r.w + b4.w, 0.f)));
        uint2 u;
        u.x = *(unsigned int*)&h01;
        u.y = *(unsigned int*)&h23;
        *(uint2*)&Xt[wv][fq * 4] = u;
    }
    __syncthreads();
    // wave wv -> output cols [wv*16, wv*16+16)
    v8h a0 = *(const v8h*)&Xt[fq & 3][quad * 8];
    v8h a1 = *(const v8h*)&Xt[fq & 3][32 + quad * 8];
    int n = wv * 16 + fq;
    v8h b0 = *(const v8h*)&WT[n * 64 + quad * 8];
    v8h b1 = *(const v8h*)&WT[n * 64 + 32 + quad * 8];
    v4f acc = (v4f){0.f, 0.f, 0.f, 0.f};
    acc = __builtin_amdgcn_mfma_f32_16x16x32_f16(a0, b0, acc, 0, 0, 0);
    acc = __builtin_amdgcn_mfma_f32_16x16x32_f16(a1, b1, acc, 0, 0, 0);
    if (quad == 0) {           // C/D rows quad*4+reg -> rows 0..3 live in quad 0
        #pragma unroll
        for (int rr = 0; rr < 4; rr++) {
            int row = blockIdx.x * 4 + rr;
            float dv = dinv[row];
            O[(size_t)row * 64 + n] = __float2half(acc[rr] * dv);
        }
    }
}

// ---------------- layer-3: agg + head-dot, write p[node] ----------------------

__global__ __launch_bounds__(256) void agg_gcn_pool(const __half* __restrict__ H,
                                                    const int* __restrict__ offs,
                                                    const int* __restrict__ csr,
                                                    const float* __restrict__ dinv,
                                                    const float* __restrict__ bias,
                                                    const float* __restrict__ fcw,
                                                    float* __restrict__ p) {
    int wid = (blockIdx.x * 256 + threadIdx.x) >> 6;
    int lane = threadIdx.x & 63;
    if (wid >= N_NODES) return;
    float4 r;
    agg_body<false>((const uint2*)H, wid, lane, offs, csr, dinv, r);
    int fq = lane & 15;
    float4 b4 = ((const float4*)bias)[fq];
    float4 f4 = ((const float4*)fcw)[fq];
    float v = fmaxf(r.x + b4.x, 0.f) * f4.x + fmaxf(r.y + b4.y, 0.f) * f4.y
            + fmaxf(r.z + b4.z, 0.f) * f4.z + fmaxf(r.w + b4.w, 0.f) * f4.w;
    v += __shfl_xor(v, 1); v += __shfl_xor(v, 2);
    v += __shfl_xor(v, 4); v += __shfl_xor(v, 8);
    if (lane == 0) p[wid] = v;
}

// ---------------- per-graph segmented mean via binary search (no atomics) ----

__device__ inline int lower_bound_batch(const int* __restrict__ batch, int key) {
    int lo = 0, hi = N_NODES;
    while (lo < hi) {
        int mid = (lo + hi) >> 1;
        if (batch[mid] < key) lo = mid + 1; else hi = mid;
    }
    return lo;
}

__global__ __launch_bounds__(256) void graph_reduce(const float* __restrict__ p,
                                                    const int* __restrict__ batch,
                                                    const float* __restrict__ fcb,
                                                    float* __restrict__ out) {
    __shared__ float red[4];
    int g = blockIdx.x;
    int s0 = lower_bound_batch(batch, g);
    int s1 = lower_bound_batch(batch, g + 1);
    float acc = 0.f;
    for (int i = s0 + threadIdx.x; i < s1; i += 256) acc += p[i];
    #pragma unroll
    for (int o = 32; o > 0; o >>= 1) acc += __shfl_xor(acc, o);
    int lane = threadIdx.x & 63, wv = threadIdx.x >> 6;
    if (lane == 0) red[wv] = acc;
    __syncthreads();
    if (threadIdx.x == 0) {
        float sum = red[0] + red[1] + red[2] + red[3];
        out[g] = sum / fmaxf((float)(s1 - s0), 1.f) + fcb[0];
    }
}

// ---------------- launch ----------------

extern "C" void kernel_launch(void* const* d_in, const int* in_sizes, int n_in,
                              void* d_out, int out_size, void* d_ws, size_t ws_size,
                              hipStream_t stream) {
    const float* x    = (const float*)d_in[0];
    const int*   ei   = (const int*)d_in[1];
    const int*   batch= (const int*)d_in[2];
    const float* w0   = (const float*)d_in[3];
    const float* b0   = (const float*)d_in[4];
    const float* w1   = (const float*)d_in[5];
    const float* b1   = (const float*)d_in[6];
    const float* w2   = (const float*)d_in[7];
    const float* b2   = (const float*)d_in[8];
    const float* fcw  = (const float*)d_in[9];
    const float* fcb  = (const float*)d_in[10];
    float* out = (float*)d_out;

    const int* src_e = ei;              // edge_index[0]
    const int* dst_e = ei + N_EDGES;    // edge_index[1]

    char* w = (char*)d_ws;
    size_t o = 0;
    int*      bcur = (int*)(w + o);      o += 256 * 16 * 4;               // padded cursors
    int*      offs = (int*)(w + o);      o += (size_t)(N_NODES + 8) * 4;  // N+1 used
    float*    dinv = (float*)(w + o);    o += (size_t)N_NODES * 4;
    _Float16* wt1  = (_Float16*)(w + o); o += 64 * 64 * 2;
    _Float16* wt2  = (_Float16*)(w + o); o += 64 * 64 * 2;
    int2*     pairs= (int2*)(w + o);     o += (size_t)NBK * CAP * 8;      // 12.85MB
    int*      csr  = (int*)(w + o);      o += (size_t)(N_EDGES + 16) * 4; // +16 pad
    __half*   bufA = (__half*)(w + o);   o += (size_t)N_NODES * 64 * 2;   // 12.8MB
    __half*   bufB = (__half*)(w + o);   o += (size_t)N_NODES * 64 * 2;   // 12.8MB
    float*    pvec = (float*)(w + o);    o += (size_t)N_NODES * 4;

    const int AGG_BLOCKS = N_NODES / 4;          // 25000, exact

    wprep<<<2, 256, 0, stream>>>(w1, w2, wt1, wt2, bcur);
    scatter_gemm<<<NCH + GEMM_BLOCKS, 256, 0, stream>>>(src_e, dst_e, bcur, pairs,
                                                        x, w0, bufA);
    bucket_place<<<2 * NBK, 256, 0, stream>>>(pairs, bcur, offs, dinv, csr);

    agg_gemm<true><<<AGG_BLOCKS, 256, 0, stream>>>(bufA, offs, csr, dinv, b0, wt1, bufB);
    agg_gemm<false><<<AGG_BLOCKS, 256, 0, stream>>>(bufB, offs, csr, dinv, b1, wt2, bufA);
    agg_gcn_pool<<<AGG_BLOCKS, 256, 0, stream>>>(bufA, offs, csr, dinv, b2, fcw, pvec);

    graph_reduce<<<N_GRAPHS, 256, 0, stream>>>(pvec, batch, fcb, out);
}

// Round 15
// 295.600 us; speedup vs baseline: 1.0139x; 1.0139x over previous
//
#include <hip/hip_runtime.h>
#include <hip/hip_fp16.h>
#include <type_traits>

#define N_NODES 100000
#define N_EDGES 1280000
#define N_GRAPHS 512
#define NBK 196          // buckets of 512 dst nodes: ceil(100000/512)
#define CHUNK 6400       // edges per scatter block; 200*6400 == N_EDGES exactly
#define NCH 200
#define CAP 8192         // per-bucket region capacity: mean 6554, sigma ~81 -> 20 sigma
#define CAPH 4096        // per-HALF-bucket LDS capacity: mean 3277, sigma ~57 -> 14 sigma
#define GEMM_BLOCKS 391  // ceil(100000/256)

typedef _Float16 v8h __attribute__((ext_vector_type(8)));
typedef float v4f __attribute__((ext_vector_type(4)));

// fp16 x fp32 + fp32 fused (one VALU op; fp16 operand widened exactly in the FMA)
__device__ inline void fmix_lo(float& acc, unsigned h2, float n) {
    asm volatile("v_fma_mix_f32 %0, %1, %2, %0 op_sel:[0,0,0] op_sel_hi:[1,0,0]"
                 : "+v"(acc) : "v"(h2), "v"(n));
}
__device__ inline void fmix_hi(float& acc, unsigned h2, float n) {
    asm volatile("v_fma_mix_f32 %0, %1, %2, %0 op_sel:[1,0,0] op_sel_hi:[1,0,0]"
                 : "+v"(acc) : "v"(h2), "v"(n));
}

// ---------------- MFMA GEMM body [256 rows x 64] @ [64 x 64] -------------------
// Wave = 16 nodes x 64 cols; A-frag A[m=lane&15][k=quad*8+j]; C/D col=lane&15,
// row=quad*4+reg (m89/m120-verified). fp32 accumulate. FOLD scales the stored
// row by dinv[row] (H' = H*dinv) enabling broadcast-norm aggregation.
// NOTE (R13 lesson): keep GEMM separate from agg — fusing them behind a block
// barrier cut the gather duty cycle ~30% and regressed.

template <typename T, bool FOLD>
__device__ inline void gemm_body(int bid, const T* __restrict__ X,
                                 const float* __restrict__ W,
                                 const float* __restrict__ dinv,
                                 __half* __restrict__ H,
                                 _Float16 (*Wt)[72]) {
    int t = threadIdx.x;
    #pragma unroll
    for (int q = 0; q < 4; q++) {         // stage + transpose W as half
        int idx = t + q * 256;
        int k = idx >> 4;
        int n0 = (idx & 15) * 4;
        float4 v = ((const float4*)W)[idx];
        Wt[n0 + 0][k] = (_Float16)v.x;
        Wt[n0 + 1][k] = (_Float16)v.y;
        Wt[n0 + 2][k] = (_Float16)v.z;
        Wt[n0 + 3][k] = (_Float16)v.w;
    }
    __syncthreads();

    int wv = t >> 6, lane = t & 63;
    int m = lane & 15, quad = lane >> 4;

    v8h bf[4][2];
    #pragma unroll
    for (int c = 0; c < 4; c++)
        #pragma unroll
        for (int h = 0; h < 2; h++)
            bf[c][h] = *(const v8h*)&Wt[c * 16 + m][h * 32 + quad * 8];

    int base = bid * 256 + wv * 64;
    #pragma unroll
    for (int tt = 0; tt < 4; tt++) {
        int tile = base + tt * 16;
        int rA = min(tile + m, N_NODES - 1);
        v8h a0, a1;
        if constexpr (std::is_same<T, float>::value) {
            const float* xp = (const float*)X + (size_t)rA * 64 + quad * 8;
            float4 p0 = *(const float4*)xp;
            float4 p1 = *(const float4*)(xp + 4);
            float4 p2 = *(const float4*)(xp + 32);
            float4 p3 = *(const float4*)(xp + 36);
            a0 = (v8h){(_Float16)p0.x, (_Float16)p0.y, (_Float16)p0.z, (_Float16)p0.w,
                       (_Float16)p1.x, (_Float16)p1.y, (_Float16)p1.z, (_Float16)p1.w};
            a1 = (v8h){(_Float16)p2.x, (_Float16)p2.y, (_Float16)p2.z, (_Float16)p2.w,
                       (_Float16)p3.x, (_Float16)p3.y, (_Float16)p3.z, (_Float16)p3.w};
        } else {
            const _Float16* xp = (const _Float16*)X + (size_t)rA * 64 + quad * 8;
            a0 = *(const v8h*)xp;
            a1 = *(const v8h*)(xp + 32);
        }
        v4f acc[4];
        #pragma unroll
        for (int c = 0; c < 4; c++) {
            acc[c] = (v4f){0.f, 0.f, 0.f, 0.f};
            acc[c] = __builtin_amdgcn_mfma_f32_16x16x32_f16(a0, bf[c][0], acc[c], 0, 0, 0);
            acc[c] = __builtin_amdgcn_mfma_f32_16x16x32_f16(a1, bf[c][1], acc[c], 0, 0, 0);
        }
        #pragma unroll
        for (int r = 0; r < 4; r++) {
            int row = tile + quad * 4 + r;
            if (row < N_NODES) {
                float dv = FOLD ? dinv[row] : 1.0f;
                __half* hp = H + (size_t)row * 64 + m;
                #pragma unroll
                for (int c = 0; c < 4; c++)
                    hp[c * 16] = __float2half(FOLD ? acc[c][r] * dv : acc[c][r]);
            }
        }
    }
}

template <typename T, bool FOLD>
__global__ __launch_bounds__(256) void gemm_mfma(const T* __restrict__ X,
                                                 const float* __restrict__ W,
                                                 const float* __restrict__ dinv,
                                                 __half* __restrict__ H) {
    __shared__ _Float16 Wt[64][72];
    gemm_body<T, FOLD>(blockIdx.x, X, W, dinv, H, Wt);
}

// ---------------- fused: edge scatter (blocks 0..NCH-1) + gemm1 (rest) ---------
// Scatter: LDS-staged, one contiguous run per bucket per block (single atomic
// on padded cursor) -> full-line writes from one CU (R5 lesson). Pairs are
// PACKED into 32 bits: (src << 9) | (dst & 511) -- src < 2^17, dst-in-bucket
// < 2^9. Halves pairs traffic and LDS, letting CHUNK double to 6400.
// gemm1 runs unfolded (dinv not yet computed); layer-1 agg uses FULL norm.

#define SC_BUF   0                              // uint[CHUNK]           25600 B
#define SC_LCNT  (CHUNK * 4)                    // int[NBK]
#define SC_LLOC  (SC_LCNT + NBK * 4)            // int[NBK]
#define SC_LCUR  (SC_LLOC + NBK * 4)            // int[NBK]
#define SC_S     (SC_LCUR + NBK * 4)            // int[256]
#define SC_BYTES (SC_S + 256 * 4)               // ~28.9 KB

__global__ __launch_bounds__(256) void scatter_gemm(const int* __restrict__ src,
                                                    const int* __restrict__ dst,
                                                    int* __restrict__ bcur,
                                                    unsigned* __restrict__ pairs,
                                                    const float* __restrict__ x,
                                                    const float* __restrict__ w0,
                                                    __half* __restrict__ H) {
    alignas(16) __shared__ char smem[SC_BYTES];
    if (blockIdx.x >= NCH) {
        gemm_body<float, false>(blockIdx.x - NCH, x, w0, nullptr, H,
                                (_Float16(*)[72])smem);
        return;
    }
    unsigned* buf  = (unsigned*)(smem + SC_BUF);
    int*      lcnt = (int*)(smem + SC_LCNT);
    int*      lloc = (int*)(smem + SC_LLOC);
    int*      lcur = (int*)(smem + SC_LCUR);
    int*      s    = (int*)(smem + SC_S);
    int t = threadIdx.x;
    for (int k = t; k < NBK; k += 256) { lcnt[k] = 0; lcur[k] = 0; }
    __syncthreads();
    int e0 = blockIdx.x * CHUNK;
    for (int i = t; i < CHUNK; i += 256) atomicAdd(&lcnt[dst[e0 + i] >> 9], 1);
    __syncthreads();
    {   // exclusive scan of lcnt (NBK <= 256)
        int v = (t < NBK) ? lcnt[t] : 0;
        s[t] = v; __syncthreads();
        for (int d = 1; d < 256; d <<= 1) {
            int xx = (t >= d) ? s[t - d] : 0;
            __syncthreads();
            s[t] += xx;
            __syncthreads();
        }
        if (t < NBK) lloc[t] = s[t] - v;
    }
    __syncthreads();
    for (int i = t; i < CHUNK; i += 256) {
        int d = dst[e0 + i];
        int k = d >> 9;
        int li = lloc[k] + atomicAdd(&lcur[k], 1);
        buf[li] = ((unsigned)src[e0 + i] << 9) | (unsigned)(d & 511);
    }
    __syncthreads();
    for (int k = t; k < NBK; k += 256) {
        int c = lcnt[k];
        if (c) {
            int g = atomicAdd(&bcur[k * 16], c);
            int lo = lloc[k];
            unsigned* dstp = pairs + (size_t)k * CAP;
            for (int j = 0; j < c; j++)
                if (g + j < CAP) dstp[g + j] = buf[lo + j];   // clamp (20-sigma)
        }
    }
}

// ---------------- per-half-bucket exact CSR + degree/dinv/offs ----------------
// 392 blocks x 256 thr: block handles 256 nodes (half a 512-node bucket); reads
// the bucket's packed pairs, filters its half. bbase computed in-block (196-int
// reduce). half1 base = bbase + (cnt - own_total).

__global__ __launch_bounds__(256) void bucket_place(const unsigned* __restrict__ pairs,
                                                    const int* __restrict__ bcur,
                                                    int* __restrict__ offs,
                                                    float* __restrict__ dinv,
                                                    int* __restrict__ csr) {
    __shared__ int lcnt[256], lofs[256], lcur[256], red[256];
    __shared__ int lsrc[CAPH];                  // 16 KB
    int t = threadIdx.x;
    int bb = blockIdx.x;
    int b = bb >> 1, half = bb & 1;
    int node0 = (b << 9) + (half << 8);
    int nn = min(256, N_NODES - node0);
    red[t] = (t < b) ? min(bcur[t * 16], CAP) : 0;
    __syncthreads();
    for (int d = 128; d > 0; d >>= 1) {
        if (t < d) red[t] += red[t + d];
        __syncthreads();
    }
    int bbase = red[0];
    int cnt = min(bcur[b * 16], CAP);
    __syncthreads();
    lcnt[t] = 0; lcur[t] = 0;
    __syncthreads();
    const unsigned* prs = pairs + (size_t)b * CAP;
    for (int i = t; i < cnt; i += 256) {
        int n = prs[i] & 511;
        if ((n >> 8) == half) atomicAdd(&lcnt[n & 255], 1);
    }
    __syncthreads();
    int deg = lcnt[t];
    red[t] = deg; __syncthreads();
    for (int d = 1; d < 256; d <<= 1) {         // inclusive scan
        int xx = (t >= d) ? red[t - d] : 0;
        __syncthreads();
        red[t] += xx;
        __syncthreads();
    }
    lofs[t] = red[t] - deg;
    int total = red[255];
    int beg = bbase + (half ? (cnt - total) : 0);
    if (t < nn) {
        offs[node0 + t] = beg + lofs[t];
        dinv[node0 + t] = 1.0f / sqrtf((float)deg + 1.0f);
    }
    __syncthreads();
    for (int i = t; i < cnt; i += 256) {
        unsigned pr = prs[i];
        int n = pr & 511;
        if ((n >> 8) == half) {
            int li = lofs[n & 255] + atomicAdd(&lcur[n & 255], 1);
            if (li < CAPH) lsrc[li] = (int)(pr >> 9);
        }
    }
    __syncthreads();
    for (int j = t; j < total; j += 256) csr[beg + j] = lsrc[j];
    if (bb == 0 && t == 0) offs[N_NODES] = N_EDGES;
}

// ------------- aggregation: wave per node, 4 edge-subgroups x 16 feature-quads -------------
// Flat predicated 4-deep gather (16 edges/chunk). FULL: H unscaled, per-edge
// weight dinv[src]*dinv[dst] (layer 1). !FULL: H pre-scaled by dinv in the
// gemm epilogue -> weight is the broadcast di only. csr padded +16; OOB slots
// read garbage but select row 0 with n=0 (predication).

template <bool FULL>
__device__ inline void agg_body(const uint2* __restrict__ Hh, int wid, int lane,
                                const int* __restrict__ offs,
                                const int* __restrict__ csr,
                                const float* __restrict__ dinv,
                                float4& out) {
    int eg = lane >> 4;       // 0..3
    int fq = lane & 15;       // feature quad
    int beg = offs[wid], end = offs[wid + 1];
    float di = dinv[wid];
    uint2 us = Hh[wid * 16 + fq];

    float4 a0 = {0.f, 0.f, 0.f, 0.f};
    float4 a1 = {0.f, 0.f, 0.f, 0.f};
    for (int base = beg; base < end; base += 16) {
        int i0 = base + eg;
        int r0 = csr[i0], r1 = csr[i0 + 4], r2 = csr[i0 + 8], r3 = csr[i0 + 12];
        bool p0 = i0      < end, p1 = i0 + 4  < end,
             p2 = i0 + 8  < end, p3 = i0 + 12 < end;
        int s0 = p0 ? r0 : 0, s1 = p1 ? r1 : 0,
            s2 = p2 ? r2 : 0, s3 = p3 ? r3 : 0;
        uint2 u0 = Hh[(s0 << 4) + fq];
        uint2 u1 = Hh[(s1 << 4) + fq];
        uint2 u2 = Hh[(s2 << 4) + fq];
        uint2 u3 = Hh[(s3 << 4) + fq];
        float n0, n1, n2, n3;
        if constexpr (FULL) {
            float d0 = dinv[s0], d1 = dinv[s1], d2 = dinv[s2], d3 = dinv[s3];
            n0 = p0 ? d0 * di : 0.f;
            n1 = p1 ? d1 * di : 0.f;
            n2 = p2 ? d2 * di : 0.f;
            n3 = p3 ? d3 * di : 0.f;
        } else {
            n0 = p0 ? di : 0.f;
            n1 = p1 ? di : 0.f;
            n2 = p2 ? di : 0.f;
            n3 = p3 ? di : 0.f;
        }
        fmix_lo(a0.x, u0.x, n0); fmix_hi(a0.y, u0.x, n0);
        fmix_lo(a0.z, u0.y, n0); fmix_hi(a0.w, u0.y, n0);
        fmix_lo(a1.x, u1.x, n1); fmix_hi(a1.y, u1.x, n1);
        fmix_lo(a1.z, u1.y, n1); fmix_hi(a1.w, u1.y, n1);
        fmix_lo(a0.x, u2.x, n2); fmix_hi(a0.y, u2.x, n2);
        fmix_lo(a0.z, u2.y, n2); fmix_hi(a0.w, u2.y, n2);
        fmix_lo(a1.x, u3.x, n3); fmix_hi(a1.y, u3.x, n3);
        fmix_lo(a1.z, u3.y, n3); fmix_hi(a1.w, u3.y, n3);
    }
    a0.x += a1.x; a0.y += a1.y; a0.z += a1.z; a0.w += a1.w;
    a0.x += __shfl_xor(a0.x, 16); a0.y += __shfl_xor(a0.y, 16);
    a0.z += __shfl_xor(a0.z, 16); a0.w += __shfl_xor(a0.w, 16);
    a0.x += __shfl_xor(a0.x, 32); a0.y += __shfl_xor(a0.y, 32);
    a0.z += __shfl_xor(a0.z, 32); a0.w += __shfl_xor(a0.w, 32);
    float2 s01 = __half22float2(*(__half2*)&us.x);
    float2 s23 = __half22float2(*(__half2*)&us.y);
    float sw = FULL ? di * di : di;   // self term: H*di^2 == H'*di
    out.x = a0.x + s01.x * sw; out.y = a0.y + s01.y * sw;
    out.z = a0.z + s23.x * sw; out.w = a0.w + s23.y * sw;
}

template <bool FULL>
__global__ __launch_bounds__(256) void agg_gcn(const __half* __restrict__ H,
                                               const int* __restrict__ offs,
                                               const int* __restrict__ csr,
                                               const float* __restrict__ dinv,
                                               const float* __restrict__ bias,
                                               __half* __restrict__ Out) {
    int wid = (blockIdx.x * 256 + threadIdx.x) >> 6;
    int lane = threadIdx.x & 63;
    if (wid >= N_NODES) return;
    float4 r;
    agg_body<FULL>((const uint2*)H, wid, lane, offs, csr, dinv, r);
    int fq = lane & 15;
    if ((lane >> 4) == 0) {
        float4 b4 = ((const float4*)bias)[fq];
        __half2 h01 = __float22half2_rn(make_float2(fmaxf(r.x + b4.x, 0.f),
                                                    fmaxf(r.y + b4.y, 0.f)));
        __half2 h23 = __float22half2_rn(make_float2(fmaxf(r.z + b4.z, 0.f),
                                                    fmaxf(r.w + b4.w, 0.f)));
        uint2 u;
        u.x = *(unsigned int*)&h01;
        u.y = *(unsigned int*)&h23;
        ((uint2*)Out)[(size_t)wid * 16 + fq] = u;
    }
}

__global__ __launch_bounds__(256) void agg_gcn_pool(const __half* __restrict__ H,
                                                    const int* __restrict__ offs,
                                                    const int* __restrict__ csr,
                                                    const float* __restrict__ dinv,
                                                    const float* __restrict__ bias,
                                                    const float* __restrict__ fcw,
                                                    float* __restrict__ p) {
    int wid = (blockIdx.x * 256 + threadIdx.x) >> 6;
    int lane = threadIdx.x & 63;
    if (wid >= N_NODES) return;
    float4 r;
    agg_body<false>((const uint2*)H, wid, lane, offs, csr, dinv, r);
    int fq = lane & 15;
    float4 b4 = ((const float4*)bias)[fq];
    float4 f4 = ((const float4*)fcw)[fq];
    float v = fmaxf(r.x + b4.x, 0.f) * f4.x + fmaxf(r.y + b4.y, 0.f) * f4.y
            + fmaxf(r.z + b4.z, 0.f) * f4.z + fmaxf(r.w + b4.w, 0.f) * f4.w;
    v += __shfl_xor(v, 1); v += __shfl_xor(v, 2);
    v += __shfl_xor(v, 4); v += __shfl_xor(v, 8);
    if (lane == 0) p[wid] = v;
}

// ---------------- per-graph segmented mean via binary search (no atomics) ----

__device__ inline int lower_bound_batch(const int* __restrict__ batch, int key) {
    int lo = 0, hi = N_NODES;
    while (lo < hi) {
        int mid = (lo + hi) >> 1;
        if (batch[mid] < key) lo = mid + 1; else hi = mid;
    }
    return lo;
}

__global__ __launch_bounds__(256) void graph_reduce(const float* __restrict__ p,
                                                    const int* __restrict__ batch,
                                                    const float* __restrict__ fcb,
                                                    float* __restrict__ out) {
    __shared__ float red[4];
    int g = blockIdx.x;
    int s0 = lower_bound_batch(batch, g);
    int s1 = lower_bound_batch(batch, g + 1);
    float acc = 0.f;
    for (int i = s0 + threadIdx.x; i < s1; i += 256) acc += p[i];
    #pragma unroll
    for (int o = 32; o > 0; o >>= 1) acc += __shfl_xor(acc, o);
    int lane = threadIdx.x & 63, wv = threadIdx.x >> 6;
    if (lane == 0) red[wv] = acc;
    __syncthreads();
    if (threadIdx.x == 0) {
        float sum = red[0] + red[1] + red[2] + red[3];
        out[g] = sum / fmaxf((float)(s1 - s0), 1.f) + fcb[0];
    }
}

// ---------------- launch ----------------

extern "C" void kernel_launch(void* const* d_in, const int* in_sizes, int n_in,
                              void* d_out, int out_size, void* d_ws, size_t ws_size,
                              hipStream_t stream) {
    const float* x    = (const float*)d_in[0];
    const int*   ei   = (const int*)d_in[1];
    const int*   batch= (const int*)d_in[2];
    const float* w0   = (const float*)d_in[3];
    const float* b0   = (const float*)d_in[4];
    const float* w1   = (const float*)d_in[5];
    const float* b1   = (const float*)d_in[6];
    const float* w2   = (const float*)d_in[7];
    const float* b2   = (const float*)d_in[8];
    const float* fcw  = (const float*)d_in[9];
    const float* fcb  = (const float*)d_in[10];
    float* out = (float*)d_out;

    const int* src_e = ei;              // edge_index[0]
    const int* dst_e = ei + N_EDGES;    // edge_index[1]

    char* w = (char*)d_ws;
    size_t o = 0;
    int*      bcur = (int*)(w + o);      o += 256 * 16 * 4;               // padded cursors
    int*      offs = (int*)(w + o);      o += (size_t)(N_NODES + 8) * 4;  // N+1 used
    float*    dinv = (float*)(w + o);    o += (size_t)N_NODES * 4;
    unsigned* pairs= (unsigned*)(w + o); o += (size_t)NBK * CAP * 4;      // 6.4MB packed
    int*      csr  = (int*)(w + o);      o += (size_t)(N_EDGES + 16) * 4; // +16 pad
    __half*   bufA = (__half*)(w + o);   o += (size_t)N_NODES * 64 * 2;   // 12.8MB
    __half*   bufB = (__half*)(w + o);   o += (size_t)N_NODES * 64 * 2;   // 12.8MB
    float*    pvec = (float*)(w + o);    o += (size_t)N_NODES * 4;

    hipMemsetAsync(bcur, 0, 256 * 16 * 4, stream);

    const int AGG_BLOCKS = N_NODES / 4;          // 25000, exact

    // scatter (200 blocks) + gemm1 unfolded (391 blocks) fused: independent work
    scatter_gemm<<<NCH + GEMM_BLOCKS, 256, 0, stream>>>(src_e, dst_e, bcur, pairs,
                                                        x, w0, bufA);
    bucket_place<<<2 * NBK, 256, 0, stream>>>(pairs, bcur, offs, dinv, csr);

    agg_gcn<true><<<AGG_BLOCKS, 256, 0, stream>>>(bufA, offs, csr, dinv, b0, bufB);

    gemm_mfma<__half, true><<<GEMM_BLOCKS, 256, 0, stream>>>(bufB, w1, dinv, bufA);
    agg_gcn<false><<<AGG_BLOCKS, 256, 0, stream>>>(bufA, offs, csr, dinv, b1, bufB);

    gemm_mfma<__half, true><<<GEMM_BLOCKS, 256, 0, stream>>>(bufB, w2, dinv, bufA);
    agg_gcn_pool<<<AGG_BLOCKS, 256, 0, stream>>>(bufA, offs, csr, dinv, b2, fcw, pvec);

    graph_reduce<<<N_GRAPHS, 256, 0, stream>>>(pvec, batch, fcb, out);
}

// Round 16
// 292.083 us; speedup vs baseline: 1.0261x; 1.0120x over previous
//
#include <hip/hip_runtime.h>
#include <hip/hip_fp16.h>
#include <type_traits>

#define N_NODES 100000
#define N_EDGES 1280000
#define N_GRAPHS 512
#define NBK 196          // buckets of 512 dst nodes: ceil(100000/512)
#define CHUNK 3200       // edges per scatter block; 400*3200 == N_EDGES exactly
#define NCH 400
#define CAP 8192         // per-bucket region capacity: mean 6554, sigma ~81 -> 20 sigma
#define CAPH 4096        // per-HALF-bucket LDS capacity: mean 3277, sigma ~57 -> 14 sigma
#define GEMM_BLOCKS 391  // ceil(100000/256)

typedef _Float16 v8h __attribute__((ext_vector_type(8)));
typedef float v4f __attribute__((ext_vector_type(4)));

// fp16 x fp32 + fp32 fused (one VALU op; fp16 operand widened exactly in the FMA)
__device__ inline void fmix_lo(float& acc, unsigned h2, float n) {
    asm volatile("v_fma_mix_f32 %0, %1, %2, %0 op_sel:[0,0,0] op_sel_hi:[1,0,0]"
                 : "+v"(acc) : "v"(h2), "v"(n));
}
__device__ inline void fmix_hi(float& acc, unsigned h2, float n) {
    asm volatile("v_fma_mix_f32 %0, %1, %2, %0 op_sel:[1,0,0] op_sel_hi:[1,0,0]"
                 : "+v"(acc) : "v"(h2), "v"(n));
}

// ---------------- MFMA GEMM body [256 rows x 64] @ [64 x 64] -------------------
// Wave = 16 nodes x 64 cols; A-frag A[m=lane&15][k=quad*8+j]; C/D col=lane&15,
// row=quad*4+reg (m89/m120-verified). fp32 accumulate. FOLD scales the stored
// row by dinv[row] (H' = H*dinv) enabling broadcast-norm aggregation.
// NOTE (R13 lesson): keep GEMM separate from agg — fusing them behind a block
// barrier cut the gather duty cycle ~30% and regressed.

template <typename T, bool FOLD>
__device__ inline void gemm_body(int bid, const T* __restrict__ X,
                                 const float* __restrict__ W,
                                 const float* __restrict__ dinv,
                                 __half* __restrict__ H,
                                 _Float16 (*Wt)[72]) {
    int t = threadIdx.x;
    #pragma unroll
    for (int q = 0; q < 4; q++) {         // stage + transpose W as half
        int idx = t + q * 256;
        int k = idx >> 4;
        int n0 = (idx & 15) * 4;
        float4 v = ((const float4*)W)[idx];
        Wt[n0 + 0][k] = (_Float16)v.x;
        Wt[n0 + 1][k] = (_Float16)v.y;
        Wt[n0 + 2][k] = (_Float16)v.z;
        Wt[n0 + 3][k] = (_Float16)v.w;
    }
    __syncthreads();

    int wv = t >> 6, lane = t & 63;
    int m = lane & 15, quad = lane >> 4;

    v8h bf[4][2];
    #pragma unroll
    for (int c = 0; c < 4; c++)
        #pragma unroll
        for (int h = 0; h < 2; h++)
            bf[c][h] = *(const v8h*)&Wt[c * 16 + m][h * 32 + quad * 8];

    int base = bid * 256 + wv * 64;
    #pragma unroll
    for (int tt = 0; tt < 4; tt++) {
        int tile = base + tt * 16;
        int rA = min(tile + m, N_NODES - 1);
        v8h a0, a1;
        if constexpr (std::is_same<T, float>::value) {
            const float* xp = (const float*)X + (size_t)rA * 64 + quad * 8;
            float4 p0 = *(const float4*)xp;
            float4 p1 = *(const float4*)(xp + 4);
            float4 p2 = *(const float4*)(xp + 32);
            float4 p3 = *(const float4*)(xp + 36);
            a0 = (v8h){(_Float16)p0.x, (_Float16)p0.y, (_Float16)p0.z, (_Float16)p0.w,
                       (_Float16)p1.x, (_Float16)p1.y, (_Float16)p1.z, (_Float16)p1.w};
            a1 = (v8h){(_Float16)p2.x, (_Float16)p2.y, (_Float16)p2.z, (_Float16)p2.w,
                       (_Float16)p3.x, (_Float16)p3.y, (_Float16)p3.z, (_Float16)p3.w};
        } else {
            const _Float16* xp = (const _Float16*)X + (size_t)rA * 64 + quad * 8;
            a0 = *(const v8h*)xp;
            a1 = *(const v8h*)(xp + 32);
        }
        v4f acc[4];
        #pragma unroll
        for (int c = 0; c < 4; c++) {
            acc[c] = (v4f){0.f, 0.f, 0.f, 0.f};
            acc[c] = __builtin_amdgcn_mfma_f32_16x16x32_f16(a0, bf[c][0], acc[c], 0, 0, 0);
            acc[c] = __builtin_amdgcn_mfma_f32_16x16x32_f16(a1, bf[c][1], acc[c], 0, 0, 0);
        }
        #pragma unroll
        for (int r = 0; r < 4; r++) {
            int row = tile + quad * 4 + r;
            if (row < N_NODES) {
                float dv = FOLD ? dinv[row] : 1.0f;
                __half* hp = H + (size_t)row * 64 + m;
                #pragma unroll
                for (int c = 0; c < 4; c++)
                    hp[c * 16] = __float2half(FOLD ? acc[c][r] * dv : acc[c][r]);
            }
        }
    }
}

template <typename T, bool FOLD>
__global__ __launch_bounds__(256) void gemm_mfma(const T* __restrict__ X,
                                                 const float* __restrict__ W,
                                                 const float* __restrict__ dinv,
                                                 __half* __restrict__ H) {
    __shared__ _Float16 Wt[64][72];
    gemm_body<T, FOLD>(blockIdx.x, X, W, dinv, H, Wt);
}

// ---------------- fused: edge scatter (blocks 0..NCH-1) + gemm1 (rest) ---------
// Scatter: LDS-staged, one contiguous run per bucket per block (single atomic
// on padded cursor) -> full-line writes from one CU (R5 lesson). Pairs PACKED
// into 32 bits: (src << 9) | (dst & 511). NCH=400 keeps scatter parallelism
// (R14 lesson: 200 blocks serialized the flush and regressed).

#define SC_BUF   0                              // uint[CHUNK]           12800 B
#define SC_LCNT  (CHUNK * 4)                    // int[NBK]
#define SC_LLOC  (SC_LCNT + NBK * 4)            // int[NBK]
#define SC_LCUR  (SC_LLOC + NBK * 4)            // int[NBK]
#define SC_S     (SC_LCUR + NBK * 4)            // int[256]
#define SC_BYTES (SC_S + 256 * 4)               // ~16.2 KB

__global__ __launch_bounds__(256) void scatter_gemm(const int* __restrict__ src,
                                                    const int* __restrict__ dst,
                                                    int* __restrict__ bcur,
                                                    unsigned* __restrict__ pairs,
                                                    const float* __restrict__ x,
                                                    const float* __restrict__ w0,
                                                    __half* __restrict__ H) {
    alignas(16) __shared__ char smem[SC_BYTES];
    if (blockIdx.x >= NCH) {
        gemm_body<float, false>(blockIdx.x - NCH, x, w0, nullptr, H,
                                (_Float16(*)[72])smem);
        return;
    }
    unsigned* buf  = (unsigned*)(smem + SC_BUF);
    int*      lcnt = (int*)(smem + SC_LCNT);
    int*      lloc = (int*)(smem + SC_LLOC);
    int*      lcur = (int*)(smem + SC_LCUR);
    int*      s    = (int*)(smem + SC_S);
    int t = threadIdx.x;
    for (int k = t; k < NBK; k += 256) { lcnt[k] = 0; lcur[k] = 0; }
    __syncthreads();
    int e0 = blockIdx.x * CHUNK;
    for (int i = t; i < CHUNK; i += 256) atomicAdd(&lcnt[dst[e0 + i] >> 9], 1);
    __syncthreads();
    {   // exclusive scan of lcnt (NBK <= 256)
        int v = (t < NBK) ? lcnt[t] : 0;
        s[t] = v; __syncthreads();
        for (int d = 1; d < 256; d <<= 1) {
            int xx = (t >= d) ? s[t - d] : 0;
            __syncthreads();
            s[t] += xx;
            __syncthreads();
        }
        if (t < NBK) lloc[t] = s[t] - v;
    }
    __syncthreads();
    for (int i = t; i < CHUNK; i += 256) {
        int d = dst[e0 + i];
        int k = d >> 9;
        int li = lloc[k] + atomicAdd(&lcur[k], 1);
        buf[li] = ((unsigned)src[e0 + i] << 9) | (unsigned)(d & 511);
    }
    __syncthreads();
    for (int k = t; k < NBK; k += 256) {
        int c = lcnt[k];
        if (c) {
            int g = atomicAdd(&bcur[k * 16], c);
            int lo = lloc[k];
            unsigned* dstp = pairs + (size_t)k * CAP;
            for (int j = 0; j < c; j++)
                if (g + j < CAP) dstp[g + j] = buf[lo + j];   // clamp (20-sigma)
        }
    }
}

// ---------------- per-half-bucket exact CSR + degree/dinv/offs ----------------
// 392 blocks x 256 thr: block handles 256 nodes (half a 512-node bucket); reads
// the bucket's packed pairs, filters its half. bbase computed in-block.

__global__ __launch_bounds__(256) void bucket_place(const unsigned* __restrict__ pairs,
                                                    const int* __restrict__ bcur,
                                                    int* __restrict__ offs,
                                                    float* __restrict__ dinv,
                                                    int* __restrict__ csr) {
    __shared__ int lcnt[256], lofs[256], lcur[256], red[256];
    __shared__ int lsrc[CAPH];                  // 16 KB
    int t = threadIdx.x;
    int bb = blockIdx.x;
    int b = bb >> 1, half = bb & 1;
    int node0 = (b << 9) + (half << 8);
    int nn = min(256, N_NODES - node0);
    red[t] = (t < b) ? min(bcur[t * 16], CAP) : 0;
    __syncthreads();
    for (int d = 128; d > 0; d >>= 1) {
        if (t < d) red[t] += red[t + d];
        __syncthreads();
    }
    int bbase = red[0];
    int cnt = min(bcur[b * 16], CAP);
    __syncthreads();
    lcnt[t] = 0; lcur[t] = 0;
    __syncthreads();
    const unsigned* prs = pairs + (size_t)b * CAP;
    for (int i = t; i < cnt; i += 256) {
        int n = prs[i] & 511;
        if ((n >> 8) == half) atomicAdd(&lcnt[n & 255], 1);
    }
    __syncthreads();
    int deg = lcnt[t];
    red[t] = deg; __syncthreads();
    for (int d = 1; d < 256; d <<= 1) {         // inclusive scan
        int xx = (t >= d) ? red[t - d] : 0;
        __syncthreads();
        red[t] += xx;
        __syncthreads();
    }
    lofs[t] = red[t] - deg;
    int total = red[255];
    int beg = bbase + (half ? (cnt - total) : 0);
    if (t < nn) {
        offs[node0 + t] = beg + lofs[t];
        dinv[node0 + t] = 1.0f / sqrtf((float)deg + 1.0f);
    }
    __syncthreads();
    for (int i = t; i < cnt; i += 256) {
        unsigned pr = prs[i];
        int n = pr & 511;
        if ((n >> 8) == half) {
            int li = lofs[n & 255] + atomicAdd(&lcur[n & 255], 1);
            if (li < CAPH) lsrc[li] = (int)(pr >> 9);
        }
    }
    __syncthreads();
    for (int j = t; j < total; j += 256) csr[beg + j] = lsrc[j];
    if (bb == 0 && t == 0) offs[N_NODES] = N_EDGES;
}

// ------------- aggregation: wave per node, 4 edge-subgroups x 16 feature-quads -------------
// Flat predicated 4-deep gather (16 edges/chunk). FULL: H unscaled, per-edge
// weight dinv[src]*dinv[dst] (layer 1). !FULL: H pre-scaled by dinv in the
// gemm epilogue -> weight is the broadcast di only. csr padded +16; OOB slots
// read garbage but select row 0 with n=0 (predication).

template <bool FULL>
__device__ inline void agg_body(const uint2* __restrict__ Hh, int wid, int lane,
                                const int* __restrict__ offs,
                                const int* __restrict__ csr,
                                const float* __restrict__ dinv,
                                float4& out) {
    int eg = lane >> 4;       // 0..3
    int fq = lane & 15;       // feature quad
    int beg = offs[wid], end = offs[wid + 1];
    float di = dinv[wid];
    uint2 us = Hh[wid * 16 + fq];

    float4 a0 = {0.f, 0.f, 0.f, 0.f};
    float4 a1 = {0.f, 0.f, 0.f, 0.f};
    for (int base = beg; base < end; base += 16) {
        int i0 = base + eg;
        int r0 = csr[i0], r1 = csr[i0 + 4], r2 = csr[i0 + 8], r3 = csr[i0 + 12];
        bool p0 = i0      < end, p1 = i0 + 4  < end,
             p2 = i0 + 8  < end, p3 = i0 + 12 < end;
        int s0 = p0 ? r0 : 0, s1 = p1 ? r1 : 0,
            s2 = p2 ? r2 : 0, s3 = p3 ? r3 : 0;
        uint2 u0 = Hh[(s0 << 4) + fq];
        uint2 u1 = Hh[(s1 << 4) + fq];
        uint2 u2 = Hh[(s2 << 4) + fq];
        uint2 u3 = Hh[(s3 << 4) + fq];
        float n0, n1, n2, n3;
        if constexpr (FULL) {
            float d0 = dinv[s0], d1 = dinv[s1], d2 = dinv[s2], d3 = dinv[s3];
            n0 = p0 ? d0 * di : 0.f;
            n1 = p1 ? d1 * di : 0.f;
            n2 = p2 ? d2 * di : 0.f;
            n3 = p3 ? d3 * di : 0.f;
        } else {
            n0 = p0 ? di : 0.f;
            n1 = p1 ? di : 0.f;
            n2 = p2 ? di : 0.f;
            n3 = p3 ? di : 0.f;
        }
        fmix_lo(a0.x, u0.x, n0); fmix_hi(a0.y, u0.x, n0);
        fmix_lo(a0.z, u0.y, n0); fmix_hi(a0.w, u0.y, n0);
        fmix_lo(a1.x, u1.x, n1); fmix_hi(a1.y, u1.x, n1);
        fmix_lo(a1.z, u1.y, n1); fmix_hi(a1.w, u1.y, n1);
        fmix_lo(a0.x, u2.x, n2); fmix_hi(a0.y, u2.x, n2);
        fmix_lo(a0.z, u2.y, n2); fmix_hi(a0.w, u2.y, n2);
        fmix_lo(a1.x, u3.x, n3); fmix_hi(a1.y, u3.x, n3);
        fmix_lo(a1.z, u3.y, n3); fmix_hi(a1.w, u3.y, n3);
    }
    a0.x += a1.x; a0.y += a1.y; a0.z += a1.z; a0.w += a1.w;
    a0.x += __shfl_xor(a0.x, 16); a0.y += __shfl_xor(a0.y, 16);
    a0.z += __shfl_xor(a0.z, 16); a0.w += __shfl_xor(a0.w, 16);
    a0.x += __shfl_xor(a0.x, 32); a0.y += __shfl_xor(a0.y, 32);
    a0.z += __shfl_xor(a0.z, 32); a0.w += __shfl_xor(a0.w, 32);
    float2 s01 = __half22float2(*(__half2*)&us.x);
    float2 s23 = __half22float2(*(__half2*)&us.y);
    float sw = FULL ? di * di : di;   // self term: H*di^2 == H'*di
    out.x = a0.x + s01.x * sw; out.y = a0.y + s01.y * sw;
    out.z = a0.z + s23.x * sw; out.w = a0.w + s23.y * sw;
}

template <bool FULL>
__global__ __launch_bounds__(256) void agg_gcn(const __half* __restrict__ H,
                                               const int* __restrict__ offs,
                                               const int* __restrict__ csr,
                                               const float* __restrict__ dinv,
                                               const float* __restrict__ bias,
                                               __half* __restrict__ Out) {
    int wid = (blockIdx.x * 256 + threadIdx.x) >> 6;
    int lane = threadIdx.x & 63;
    if (wid >= N_NODES) return;
    float4 r;
    agg_body<FULL>((const uint2*)H, wid, lane, offs, csr, dinv, r);
    int fq = lane & 15;
    if ((lane >> 4) == 0) {
        float4 b4 = ((const float4*)bias)[fq];
        __half2 h01 = __float22half2_rn(make_float2(fmaxf(r.x + b4.x, 0.f),
                                                    fmaxf(r.y + b4.y, 0.f)));
        __half2 h23 = __float22half2_rn(make_float2(fmaxf(r.z + b4.z, 0.f),
                                                    fmaxf(r.w + b4.w, 0.f)));
        uint2 u;
        u.x = *(unsigned int*)&h01;
        u.y = *(unsigned int*)&h23;
        ((uint2*)Out)[(size_t)wid * 16 + fq] = u;
    }
}

__global__ __launch_bounds__(256) void agg_gcn_pool(const __half* __restrict__ H,
                                                    const int* __restrict__ offs,
                                                    const int* __restrict__ csr,
                                                    const float* __restrict__ dinv,
                                                    const float* __restrict__ bias,
                                                    const float* __restrict__ fcw,
                                                    float* __restrict__ p) {
    int wid = (blockIdx.x * 256 + threadIdx.x) >> 6;
    int lane = threadIdx.x & 63;
    if (wid >= N_NODES) return;
    float4 r;
    agg_body<false>((const uint2*)H, wid, lane, offs, csr, dinv, r);
    int fq = lane & 15;
    float4 b4 = ((const float4*)bias)[fq];
    float4 f4 = ((const float4*)fcw)[fq];
    float v = fmaxf(r.x + b4.x, 0.f) * f4.x + fmaxf(r.y + b4.y, 0.f) * f4.y
            + fmaxf(r.z + b4.z, 0.f) * f4.z + fmaxf(r.w + b4.w, 0.f) * f4.w;
    v += __shfl_xor(v, 1); v += __shfl_xor(v, 2);
    v += __shfl_xor(v, 4); v += __shfl_xor(v, 8);
    if (lane == 0) p[wid] = v;
}

// ---------------- per-graph segmented mean via binary search (no atomics) ----

__device__ inline int lower_bound_batch(const int* __restrict__ batch, int key) {
    int lo = 0, hi = N_NODES;
    while (lo < hi) {
        int mid = (lo + hi) >> 1;
        if (batch[mid] < key) lo = mid + 1; else hi = mid;
    }
    return lo;
}

__global__ __launch_bounds__(256) void graph_reduce(const float* __restrict__ p,
                                                    const int* __restrict__ batch,
                                                    const float* __restrict__ fcb,
                                                    float* __restrict__ out) {
    __shared__ float red[4];
    int g = blockIdx.x;
    int s0 = lower_bound_batch(batch, g);
    int s1 = lower_bound_batch(batch, g + 1);
    float acc = 0.f;
    for (int i = s0 + threadIdx.x; i < s1; i += 256) acc += p[i];
    #pragma unroll
    for (int o = 32; o > 0; o >>= 1) acc += __shfl_xor(acc, o);
    int lane = threadIdx.x & 63, wv = threadIdx.x >> 6;
    if (lane == 0) red[wv] = acc;
    __syncthreads();
    if (threadIdx.x == 0) {
        float sum = red[0] + red[1] + red[2] + red[3];
        out[g] = sum / fmaxf((float)(s1 - s0), 1.f) + fcb[0];
    }
}

// ---------------- launch ----------------

extern "C" void kernel_launch(void* const* d_in, const int* in_sizes, int n_in,
                              void* d_out, int out_size, void* d_ws, size_t ws_size,
                              hipStream_t stream) {
    const float* x    = (const float*)d_in[0];
    const int*   ei   = (const int*)d_in[1];
    const int*   batch= (const int*)d_in[2];
    const float* w0   = (const float*)d_in[3];
    const float* b0   = (const float*)d_in[4];
    const float* w1   = (const float*)d_in[5];
    const float* b1   = (const float*)d_in[6];
    const float* w2   = (const float*)d_in[7];
    const float* b2   = (const float*)d_in[8];
    const float* fcw  = (const float*)d_in[9];
    const float* fcb  = (const float*)d_in[10];
    float* out = (float*)d_out;

    const int* src_e = ei;              // edge_index[0]
    const int* dst_e = ei + N_EDGES;    // edge_index[1]

    char* w = (char*)d_ws;
    size_t o = 0;
    int*      bcur = (int*)(w + o);      o += 256 * 16 * 4;               // padded cursors
    int*      offs = (int*)(w + o);      o += (size_t)(N_NODES + 8) * 4;  // N+1 used
    float*    dinv = (float*)(w + o);    o += (size_t)N_NODES * 4;
    unsigned* pairs= (unsigned*)(w + o); o += (size_t)NBK * CAP * 4;      // 6.4MB packed
    int*      csr  = (int*)(w + o);      o += (size_t)(N_EDGES + 16) * 4; // +16 pad
    __half*   bufA = (__half*)(w + o);   o += (size_t)N_NODES * 64 * 2;   // 12.8MB
    __half*   bufB = (__half*)(w + o);   o += (size_t)N_NODES * 64 * 2;   // 12.8MB
    float*    pvec = (float*)(w + o);    o += (size_t)N_NODES * 4;

    hipMemsetAsync(bcur, 0, 256 * 16 * 4, stream);

    const int AGG_BLOCKS = N_NODES / 4;          // 25000, exact

    // scatter (400 blocks) + gemm1 unfolded (391 blocks) fused: independent work
    scatter_gemm<<<NCH + GEMM_BLOCKS, 256, 0, stream>>>(src_e, dst_e, bcur, pairs,
                                                        x, w0, bufA);
    bucket_place<<<2 * NBK, 256, 0, stream>>>(pairs, bcur, offs, dinv, csr);

    agg_gcn<true><<<AGG_BLOCKS, 256, 0, stream>>>(bufA, offs, csr, dinv, b0, bufB);

    gemm_mfma<__half, true><<<GEMM_BLOCKS, 256, 0, stream>>>(bufB, w1, dinv, bufA);
    agg_gcn<false><<<AGG_BLOCKS, 256, 0, stream>>>(bufA, offs, csr, dinv, b1, bufB);

    gemm_mfma<__half, true><<<GEMM_BLOCKS, 256, 0, stream>>>(bufB, w2, dinv, bufA);
    agg_gcn_pool<<<AGG_BLOCKS, 256, 0, stream>>>(bufA, offs, csr, dinv, b2, fcw, pvec);

    graph_reduce<<<N_GRAPHS, 256, 0, stream>>>(pvec, batch, fcb, out);
}